// Round 3
// 265.880 us; speedup vs baseline: 1.0495x; 1.0495x over previous
//
#include <hip/hip_runtime.h>

#define E_CNT 2000000
#define N_CNT 200000
#define B_CNT 100
#define R_CNT 13
#define G_CNT 512
#define T_CNT 10
#define OE_CNT 4

// Interleaved packed table: P2[b][g][32]  (h r=0..12 at [0..12], o r=0..12 at
// [16..28], pads zeroed).  Row = 128 B; rows (b,idx) and (b,idx+1) are the
// 256 B contiguous span one edge needs for BOTH tables.
// Size = 100*512*32*4 = 6.55 MB -> workspace.
#define P2_ROW 32
#define P2_FLOATS ((size_t)B_CNT * G_CNT * P2_ROW)
#define P2_BYTES (P2_FLOATS * 4)

#define EDGES_PER_BLOCK 64
#define EDGE_BLOCKS (E_CNT / EDGES_PER_BLOCK)       // 31250, exact
#define NODE_BLOCKS ((N_CNT + 255) / 256)           // 782
#define OUT_OVL_OFF ((size_t)E_CNT * R_CNT)
#define OUT_NODE_OFF ((size_t)2 * E_CNT * R_CNT)

#define SH_STRIDE 20                                 // padded, 80B

// Native vector type usable with __builtin_nontemporal_{load,store}.
typedef float v4f __attribute__((ext_vector_type(4)));

// One thread per (b,g): coalesced reads (lanes stride over g), full-line
// 128B row writes.  Grid 200 blocks.
__global__ __launch_bounds__(256) void repack_interleave_kernel(
    const float* __restrict__ hopping,
    const float* __restrict__ overlap,
    float* __restrict__ P2)
{
    int tid = blockIdx.x * 256 + threadIdx.x;       // 0..51199 = b*512+g
    int b = tid >> 9;
    int g = tid & (G_CNT - 1);
    float h[16], o[16];
    #pragma unroll
    for (int r = 0; r < R_CNT; ++r) {
        size_t src = (((size_t)b * R_CNT + r) << 9) + g;   // lanes: consecutive g
        h[r] = hopping[src];
        o[r] = overlap[src];
    }
    h[13] = h[14] = h[15] = 0.0f;
    o[13] = o[14] = o[15] = 0.0f;
    float* dst = P2 + (size_t)tid * P2_ROW;
    #pragma unroll
    for (int q = 0; q < 4; ++q) {
        v4f hv = { h[4*q], h[4*q+1], h[4*q+2], h[4*q+3] };
        v4f ov = { o[4*q], o[4*q+1], o[4*q+2], o[4*q+3] };
        *(v4f*)(dst + 4 * q)      = hv;
        *(v4f*)(dst + 16 + 4 * q) = ov;
    }
}

__global__ __launch_bounds__(256) void fused_kernel(
    const float* __restrict__ rij,
    const int*   __restrict__ edge_type,
    const float* __restrict__ P2,
    const int*   __restrict__ atom_type,
    const float* __restrict__ onsite,
    float* __restrict__ out)
{
    if (blockIdx.x < EDGE_BLOCKS) {
        __shared__ float shh[EDGES_PER_BLOCK * SH_STRIDE];
        __shared__ float sho[EDGES_PER_BLOCK * SH_STRIDE];

        int tid = threadIdx.x;
        int eL = tid >> 2;            // 0..63
        int j  = tid & 3;             // 0..3
        int e  = blockIdx.x * EDGES_PER_BLOCK + eL;

        // Read-once streams: nontemporal so they don't evict the table from L2.
        float r = __builtin_nontemporal_load(rij + e);
        int   b = __builtin_nontemporal_load(edge_type + e);

        // xx = linspace(1,6,512): closed-form interval + fraction.
        const float inv_dx = 511.0f / 5.0f;
        float s = (r - 1.0f) * inv_dx;
        int idx = (int)s;
        idx = max(0, min(G_CNT - 2, idx));
        float t = s - (float)idx;
        float omt = 1.0f - t;

        // One 256 B contiguous random span serves both tables at both grid pts.
        const float* row = P2 + ((size_t)((b << 9) + idx)) * P2_ROW + 4 * j;
        v4f h0 = *(const v4f*)(row);
        v4f h1 = *(const v4f*)(row + P2_ROW);
        v4f o0 = *(const v4f*)(row + 16);
        v4f o1 = *(const v4f*)(row + 16 + P2_ROW);

        v4f vh = h0 * omt + h1 * t;
        v4f vo = o0 * omt + o1 * t;

        *(v4f*)(shh + eL * SH_STRIDE + 4 * j) = vh;
        *(v4f*)(sho + eL * SH_STRIDE + 4 * j) = vo;
        __syncthreads();

        // Coalesced write-out: 64*13 = 832 floats = 208 float4 per table.
        if (tid < 208) {
            unsigned f0 = (unsigned)tid * 4u;
            float ph[4], po[4];
            #pragma unroll
            for (int k = 0; k < 4; ++k) {
                unsigned f = f0 + k;
                unsigned ee = f / 13u;
                unsigned rr = f - ee * 13u;
                ph[k] = shh[ee * SH_STRIDE + rr];
                po[k] = sho[ee * SH_STRIDE + rr];
            }
            v4f qh = { ph[0], ph[1], ph[2], ph[3] };
            v4f qo = { po[0], po[1], po[2], po[3] };
            size_t ob = (size_t)blockIdx.x * (EDGES_PER_BLOCK * R_CNT) + f0;
            __builtin_nontemporal_store(qh, (v4f*)(out + ob));
            __builtin_nontemporal_store(qo, (v4f*)(out + OUT_OVL_OFF + ob));
        }
    } else {
        int n = (blockIdx.x - EDGE_BLOCKS) * 256 + threadIdx.x;
        if (n < N_CNT) {
            int t = atom_type[n];
            v4f v = { onsite[t * OE_CNT + 0],
                      onsite[t * OE_CNT + 1],
                      onsite[t * OE_CNT + 2],
                      onsite[t * OE_CNT + 3] };
            __builtin_nontemporal_store(v, (v4f*)(out + OUT_NODE_OFF + (size_t)n * OE_CNT));
        }
    }
}

// Fallback (round-1 style) if workspace is too small for the packed table.
__global__ __launch_bounds__(256) void dftbsk_fallback(
    const float* __restrict__ rij,
    const int*   __restrict__ edge_type,
    const int*   __restrict__ atom_type,
    const float* __restrict__ xx,
    const float* __restrict__ hopping,
    const float* __restrict__ overlap,
    const float* __restrict__ onsite,
    float*       __restrict__ out)
{
    __shared__ float sxx[G_CNT];
    for (int i = threadIdx.x; i < G_CNT; i += blockDim.x) sxx[i] = xx[i];
    __syncthreads();

    long long gid = (long long)blockIdx.x * blockDim.x + threadIdx.x;
    if (gid < E_CNT) {
        int e = (int)gid;
        float r = rij[e];
        int b = edge_type[e];
        const float inv_dx = (float)(G_CNT - 1) / 5.0f;
        int idx = (int)floorf((r - 1.0f) * inv_dx);
        idx = max(0, min(G_CNT - 2, idx));
        while (idx > 0 && r < sxx[idx]) --idx;
        while (idx < G_CNT - 2 && r >= sxx[idx + 1]) ++idx;
        float x0 = sxx[idx], x1 = sxx[idx + 1];
        float t = (r - x0) / (x1 - x0);
        float omt = 1.0f - t;
        const float* hb = hopping + (size_t)b * (R_CNT * G_CNT) + idx;
        const float* ob = overlap + (size_t)b * (R_CNT * G_CNT) + idx;
        float* outh = out + (size_t)e * R_CNT;
        float* outo = out + OUT_OVL_OFF + (size_t)e * R_CNT;
        #pragma unroll
        for (int rr = 0; rr < R_CNT; ++rr)
            outh[rr] = hb[rr * G_CNT] * omt + hb[rr * G_CNT + 1] * t;
        #pragma unroll
        for (int rr = 0; rr < R_CNT; ++rr)
            outo[rr] = ob[rr * G_CNT] * omt + ob[rr * G_CNT + 1] * t;
    } else if (gid < (long long)E_CNT + N_CNT) {
        int n = (int)(gid - E_CNT);
        int t = atom_type[n];
        float4 v;
        v.x = onsite[t * OE_CNT + 0];
        v.y = onsite[t * OE_CNT + 1];
        v.z = onsite[t * OE_CNT + 2];
        v.w = onsite[t * OE_CNT + 3];
        *(float4*)(out + OUT_NODE_OFF + (size_t)n * OE_CNT) = v;
    }
}

extern "C" void kernel_launch(void* const* d_in, const int* in_sizes, int n_in,
                              void* d_out, int out_size, void* d_ws, size_t ws_size,
                              hipStream_t stream) {
    const float* rij        = (const float*)d_in[0];
    const int*   edge_type  = (const int*)d_in[1];
    const int*   atom_type  = (const int*)d_in[2];
    const float* xx         = (const float*)d_in[3];
    const float* hopping    = (const float*)d_in[4];
    const float* overlap    = (const float*)d_in[5];
    const float* onsite     = (const float*)d_in[6];
    float* out = (float*)d_out;

    if (ws_size >= P2_BYTES) {
        float* P2 = (float*)d_ws;
        repack_interleave_kernel<<<(B_CNT * G_CNT) / 256, 256, 0, stream>>>(
            hopping, overlap, P2);
        fused_kernel<<<EDGE_BLOCKS + NODE_BLOCKS, 256, 0, stream>>>(
            rij, edge_type, P2, atom_type, onsite, out);
    } else {
        const long long total = (long long)E_CNT + N_CNT;
        const int grid = (int)((total + 255) / 256);
        dftbsk_fallback<<<grid, 256, 0, stream>>>(rij, edge_type, atom_type, xx,
                                                  hopping, overlap, onsite, out);
    }
}